// Round 3
// baseline (599.707 us; speedup 1.0000x reference)
//
#include <hip/hip_runtime.h>
#include <hip/hip_bf16.h>
#include <cstdint>
#include <cstddef>

typedef __bf16 bf16_t;
typedef __bf16 bf16x8 __attribute__((ext_vector_type(8)));
typedef __bf16 bf16x4 __attribute__((ext_vector_type(4)));
typedef float  floatx4 __attribute__((ext_vector_type(4)));

#define DEV static __device__ __forceinline__

DEV float sigm(float x) { return 1.f / (1.f + __expf(-x)); }

constexpr int E_ = 80000;   // edges
constexpr int N_ = 40000;   // nodes
// H = 128, IN = 384, NODE_FDIM = 256, MAX_NB = 6

// ---------------------------------------------------------------------------
// detect: classify input float width (bf16 vs f32) and index width (i32/i64).
// flags[0]=1 -> floats are f32; flags[1]=1 -> idx are i64.  (unchanged)
// ---------------------------------------------------------------------------
__global__ void detect(const void* fmess, const void* bgraph, int* flags) {
  if (threadIdx.x == 0 && blockIdx.x == 0) {
    const uint16_t* w = (const uint16_t*)fmess;
    int good = 0;
    for (int j = 0; j < 128; ++j) {
      uint16_t x = w[j];
      int e = (x >> 7) & 0xFF;
      if (x == 0 || x == 0x8000 || (e >= 100 && e <= 140)) ++good;
    }
    flags[0] = (good < 110) ? 1 : 0;
    const uint32_t* q = (const uint32_t*)bgraph;
    int zeros = 0;
    for (int j = 0; j < 128; ++j)
      if (q[2 * j + 1] == 0u) ++zeros;
    flags[1] = (zeros >= 120) ? 1 : 0;
  }
}

DEV float rdf(const void* p, size_t i, bool f32) {
  return f32 ? ((const float*)p)[i] : (float)((const bf16_t*)p)[i];
}

// ---------------------------------------------------------------------------
// prep: dtype-aware transposed weight copies (BT[n][k] = W[k][n]) + bf16 bias
// copies.  WzT/WhT [128,512], WrT/WoT [128,384], UrT [128,128].  (unchanged)
// ---------------------------------------------------------------------------
__launch_bounds__(256)
__global__ void prep(const void* Wz, const void* Wr, const void* Ur,
                     const void* Wh, const void* Wo,
                     const void* bz, const void* bur, const void* bh,
                     const void* bo, const int* flags,
                     bf16_t* WzT, bf16_t* WhT, bf16_t* WrT, bf16_t* UrT,
                     bf16_t* WoT, bf16_t* bzB, bf16_t* burB, bf16_t* bhB,
                     bf16_t* boB) {
  const bool f32 = flags[0] != 0;
  int i = blockIdx.x * blockDim.x + threadIdx.x;   // 65536 threads
  {  // 128 x 512
    int j = i >> 9, k = i & 511;
    WzT[i] = (bf16_t)rdf(Wz, (size_t)k * 128 + j, f32);
    WhT[i] = (bf16_t)rdf(Wh, (size_t)k * 128 + j, f32);
  }
  if (i < 128 * 384) {
    int j = i / 384, k = i % 384;
    WrT[i] = (bf16_t)rdf(Wr, (size_t)k * 128 + j, f32);
    WoT[i] = (bf16_t)rdf(Wo, (size_t)k * 128 + j, f32);
  }
  if (i < 128 * 128) {
    int j = i >> 7, k = i & 127;
    UrT[i] = (bf16_t)rdf(Ur, (size_t)k * 128 + j, f32);
  }
  if (i < 128) {
    bzB[i]  = (bf16_t)rdf(bz, i, f32);
    burB[i] = (bf16_t)rdf(bur, i, f32);
    bhB[i]  = (bf16_t)rdf(bh, i, f32);
    boB[i]  = (bf16_t)rdf(bo, i, f32);
  }
}

// ---------------------------------------------------------------------------
// idx_cvt: normalize agraph/bgraph to int32 ws copies.  (unchanged)
// ---------------------------------------------------------------------------
__launch_bounds__(256)
__global__ void idx_cvt(const void* ag, const void* bg, int* aI, int* bI,
                        const int* flags) {
  const bool i64 = flags[1] != 0;
  int i = blockIdx.x * blockDim.x + threadIdx.x;   // 480000 threads
  if (i < N_ * 6)
    aI[i] = i64 ? (int)((const long long*)ag)[i] : ((const int*)ag)[i];
  if (i < E_ * 6)
    bI[i] = i64 ? (int)((const long long*)bg)[i] : ((const int*)bg)[i];
}

// ---------------------------------------------------------------------------
// MFMA GEMM, LDS double-buffered (BM=128, BN=128, BK=32; 8 waves 2m x 4n;
// wave tile 64x32).  Slot-swizzle (2-way bank aliasing = free): slot s of
// row r holds global k-quad q = s ^ ((r>>1)&3); applied on the global source
// for global_load_lds (linear LDS dest), inverse on ds_read.
// f32 A inputs are converted in-register during staging (reg load + cvt +
// ds_write_b128 into the same slot) -- no separate cvt pass.
//
// MODE 0: Cb = acc0 + bias0                     (single B; A0 over K0)
// MODE 2: Cf = relu(acc0 + bias0), row0=0       (A0 over K0 + A1a over K1)
// MODE 3: pz = acc0+bias0, ph = acc1+bias1 ; F0=pz, F1=ph (f32);
//         Cb = sig(pz)*tanh(ph), row0=0        (dual B, shared A0 over K0)
// MODE 4: K0=0; acc0 = A1a@Ba, acc1 = A1b@Bb over K1;
//         z = sig(acc0+F0), ph = tanh(acc1+F1), v = (1-z)*Sb + z*ph, row0=0;
//         Cb = v (+ optional Cf)
// ---------------------------------------------------------------------------
DEV void gld16(const bf16_t* g, bf16_t* l) {
  __builtin_amdgcn_global_load_lds(
      (const __attribute__((address_space(1))) void*)g,
      (__attribute__((address_space(3))) void*)l, 16, 0, 0);
}

DEV floatx4 mfma16(bf16x8 a, bf16x8 b, floatx4 c) {
  return __builtin_amdgcn_mfma_f32_16x16x32_bf16(a, b, c, 0, 0, 0);
}

template <int K0, int K1, int MODE>
__launch_bounds__(512, 4)
__global__ void mgemm(const bf16_t* A0h, const float* A0f, int lda0, int a0dyn,
                      const bf16_t* A1a, const bf16_t* A1b,
                      const bf16_t* Ba, const bf16_t* Bb, int ldb,
                      const int* flags,
                      const bf16_t* bias0, const bf16_t* bias1,
                      const bf16_t* Sb, float* F0, float* F1,
                      bf16_t* Cb, float* Cf, int Mrows) {
  constexpr int NT0 = K0 / 32, NT1 = K1 / 32, NT = NT0 + NT1;
  constexpr bool DUALB = (MODE == 3 || MODE == 4);
  constexpr int NTILES = (MODE == 4) ? 4 : (MODE == 3 ? 3 : 2);
  // tile slots (x4096 elems): 0=A, 1=Ba, 2=Bb (DUALB), 3=A1b (MODE4)
  __shared__ bf16_t lds[2][NTILES * 128 * 32];

  const bool aF32 = a0dyn && (flags[0] != 0);

  const int tid  = threadIdx.x;
  const int w    = tid >> 6, lane = tid & 63;
  const int wm   = w >> 2, wn = w & 3;
  const int lr   = lane & 15, kg = lane >> 4;
  const int rowBase = blockIdx.x * 128;

  // staging lane map: each wave stages 16 rows/cols per tile
  const int rr = lane >> 2, sq = lane & 3;
  const int r  = w * 16 + rr;                   // tile row (A) / col (B)
  const int q  = sq ^ ((r >> 1) & 3);           // global k-quad for this slot
  const int ldsOff = w * 512;                   // elems; wave-uniform base
  int gRowA = rowBase + r;
  if (gRowA > Mrows - 1) gRowA = Mrows - 1;     // tail clamp

  floatx4 acc0[4][2] = {};
  floatx4 acc1[4][2] = {};

  auto stage = [&](int kt, int buf) {
    if (kt < NT0) {
      int kk = kt * 32 + q * 8;
      if (aF32) {
        const float* ap = A0f + (size_t)gRowA * lda0 + kk;
        floatx4 x0 = *(const floatx4*)ap;
        floatx4 x1 = *(const floatx4*)(ap + 4);
        bf16x8 o;
#pragma unroll
        for (int j = 0; j < 4; ++j) { o[j] = (bf16_t)x0[j]; o[4 + j] = (bf16_t)x1[j]; }
        *(bf16x8*)(&lds[buf][0] + ldsOff + lane * 8) = o;
      } else {
        gld16(A0h + (size_t)gRowA * lda0 + kk, &lds[buf][0] + ldsOff);
      }
    } else {
      int kk = (kt - NT0) * 32 + q * 8;
      gld16(A1a + (size_t)gRowA * K1 + kk, &lds[buf][0] + ldsOff);
      if constexpr (MODE == 4)
        gld16(A1b + (size_t)gRowA * K1 + kk, &lds[buf][3 * 4096] + ldsOff);
    }
    gld16(Ba + (size_t)r * ldb + kt * 32 + q * 8, &lds[buf][4096] + ldsOff);
    if constexpr (DUALB)
      gld16(Bb + (size_t)r * ldb + kt * 32 + q * 8, &lds[buf][2 * 4096] + ldsOff);
  };

  auto compute = [&](int buf) {
    const bf16_t* L = lds[buf];
    bf16x8 b0[2], b1[2];
#pragma unroll
    for (int ni = 0; ni < 2; ++ni) {
      int c = wn * 32 + ni * 16 + lr;
      int s = kg ^ ((c >> 1) & 3);
      b0[ni] = *(const bf16x8*)(L + 4096 + c * 32 + s * 8);
      if constexpr (DUALB)
        b1[ni] = *(const bf16x8*)(L + 2 * 4096 + c * 32 + s * 8);
    }
#pragma unroll
    for (int mi = 0; mi < 4; ++mi) {
      int rA = wm * 64 + mi * 16 + lr;
      int s  = kg ^ ((rA >> 1) & 3);
      bf16x8 a0 = *(const bf16x8*)(L + rA * 32 + s * 8);
#pragma unroll
      for (int ni = 0; ni < 2; ++ni)
        acc0[mi][ni] = mfma16(a0, b0[ni], acc0[mi][ni]);
      if constexpr (MODE == 3) {
#pragma unroll
        for (int ni = 0; ni < 2; ++ni)
          acc1[mi][ni] = mfma16(a0, b1[ni], acc1[mi][ni]);
      } else if constexpr (MODE == 4) {
        bf16x8 ah = *(const bf16x8*)(L + 3 * 4096 + rA * 32 + s * 8);
#pragma unroll
        for (int ni = 0; ni < 2; ++ni)
          acc1[mi][ni] = mfma16(ah, b1[ni], acc1[mi][ni]);
      }
    }
  };

  stage(0, 0);
  __syncthreads();
  int cur = 0;
#pragma unroll 1
  for (int kt = 0; kt < NT; ++kt) {
    if (kt + 1 < NT) stage(kt + 1, cur ^ 1);
    compute(cur);
    __syncthreads();
    cur ^= 1;
  }

#pragma unroll
  for (int mi = 0; mi < 4; ++mi) {
#pragma unroll
    for (int ni = 0; ni < 2; ++ni) {
      const int col = wn * 32 + ni * 16 + lr;
#pragma unroll
      for (int r4 = 0; r4 < 4; ++r4) {
        const int row = rowBase + wm * 64 + mi * 16 + kg * 4 + r4;
        if (row < Mrows) {
          const size_t o = (size_t)row * 128 + col;
          float x0 = acc0[mi][ni][r4];
          if constexpr (MODE == 0) {
            float v = x0 + (bias0 ? (float)bias0[col] : 0.f);
            Cb[o] = (bf16_t)v;
          } else if constexpr (MODE == 2) {
            float v = fmaxf(x0 + (float)bias0[col], 0.f);
            if (row == 0) v = 0.f;
            Cf[o] = v;
          } else if constexpr (MODE == 3) {
            float pz = x0 + (float)bias0[col];
            float ph = acc1[mi][ni][r4] + (float)bias1[col];
            F0[o] = pz;
            F1[o] = ph;
            float v = sigm(pz) * tanhf(ph);
            if (row == 0) v = 0.f;
            Cb[o] = (bf16_t)v;
          } else {  // MODE 4
            float pz = x0 + F0[o];
            float ph = acc1[mi][ni][r4] + F1[o];
            float z  = sigm(pz);
            float th = tanhf(ph);
            float sI = (float)Sb[o];
            float v  = (1.f - z) * sI + z * th;
            if (row == 0) v = 0.f;
            Cb[o] = (bf16_t)v;
            if (Cf) Cf[o] = v;
          }
        }
      }
    }
  }
}

// ---------------------------------------------------------------------------
// Gather+reduce per edge: S = sum h_nei, T = sum sigmoid(Mr + G_nei) * h_nei
// 16 threads/edge, bf16x8 (16B) loads.  (unchanged)
// ---------------------------------------------------------------------------
__launch_bounds__(256)
__global__ void depth_gather(const bf16_t* h, const bf16_t* G, const bf16_t* Mr,
                             const int* bgraph, bf16_t* S, bf16_t* T) {
  int t = threadIdx.x;
  int e = blockIdx.x * 16 + (t >> 4);
  int c8 = (t & 15) * 8;
  bf16x8 mr = *(const bf16x8*)(Mr + (size_t)e * 128 + c8);
  float mrf[8];
#pragma unroll
  for (int j = 0; j < 8; ++j) mrf[j] = (float)mr[j];
  float sa[8] = {}, ta[8] = {};
  const int* bg = bgraph + (size_t)e * 6;
#pragma unroll
  for (int n = 0; n < 6; ++n) {
    int idx = bg[n];
    bf16x8 h8 = *(const bf16x8*)(h + (size_t)idx * 128 + c8);
    bf16x8 g8 = *(const bf16x8*)(G + (size_t)idx * 128 + c8);
#pragma unroll
    for (int j = 0; j < 8; ++j) {
      float hv = (float)h8[j];
      float rg = sigm(mrf[j] + (float)g8[j]);
      sa[j] += hv;
      ta[j] += rg * hv;
    }
  }
  bf16x8 sv, tv;
#pragma unroll
  for (int j = 0; j < 8; ++j) { sv[j] = (bf16_t)sa[j]; tv[j] = (bf16_t)ta[j]; }
  *(bf16x8*)(S + (size_t)e * 128 + c8) = sv;
  *(bf16x8*)(T + (size_t)e * 128 + c8) = tv;
}

// ---------------------------------------------------------------------------
// Node gather: NM[v] = sum_n h[agraph[v,n]]   (unchanged)
// ---------------------------------------------------------------------------
__launch_bounds__(256)
__global__ void nm_gather(const bf16_t* h, const int* agraph, bf16_t* NM) {
  int t = threadIdx.x;
  int v = blockIdx.x * 16 + (t >> 4);
  int c8 = (t & 15) * 8;
  float sa[8] = {};
  const int* ag = agraph + (size_t)v * 6;
#pragma unroll
  for (int n = 0; n < 6; ++n) {
    int idx = ag[n];
    bf16x8 h8 = *(const bf16x8*)(h + (size_t)idx * 128 + c8);
#pragma unroll
    for (int j = 0; j < 8; ++j) sa[j] += (float)h8[j];
  }
  bf16x8 o;
#pragma unroll
  for (int j = 0; j < 8; ++j) o[j] = (bf16_t)sa[j];
  *(bf16x8*)(NM + (size_t)v * 128 + c8) = o;
}

// ---------------------------------------------------------------------------
extern "C" void kernel_launch(void* const* d_in, const int* in_sizes, int n_in,
                              void* d_out, int out_size, void* d_ws, size_t ws_size,
                              hipStream_t stream) {
  const void* fnode  = d_in[0];
  const void* fmess  = d_in[1];
  const void* agraph = d_in[2];
  const void* bgraph = d_in[3];
  const void* Wz  = d_in[4];
  const void* bz  = d_in[5];
  const void* Wr  = d_in[6];
  const void* Ur  = d_in[7];
  const void* bur = d_in[8];
  const void* Wh  = d_in[9];
  const void* bh  = d_in[10];
  const void* Wo  = d_in[11];
  const void* bo  = d_in[12];

  // workspace (~210 MB): 6 x [E,128] bf16 + 2 x [E,128] f32 + weights + idx
  char* ws = (char*)d_ws;
  bf16_t* Mr  = (bf16_t*)ws; ws += (size_t)E_ * 128 * 2;  // fmess@Wr + bur
  bf16_t* G   = (bf16_t*)ws; ws += (size_t)E_ * 128 * 2;  // h@Ur; later NM
  bf16_t* S   = (bf16_t*)ws; ws += (size_t)E_ * 128 * 2;  // sum h_nei
  bf16_t* T   = (bf16_t*)ws; ws += (size_t)E_ * 128 * 2;  // sum r*h_nei
  bf16_t* hP0 = (bf16_t*)ws; ws += (size_t)E_ * 128 * 2;  // h ping
  bf16_t* hP1 = (bf16_t*)ws; ws += (size_t)E_ * 128 * 2;  // h pong
  float*  PzF = (float*)ws;  ws += (size_t)E_ * 128 * 4;  // fmess@Wz1 + bz (f32)
  float*  PhF = (float*)ws;  ws += (size_t)E_ * 128 * 4;  // fmess@Wh1 + bh (f32)
  bf16_t* WzT = (bf16_t*)ws; ws += 128 * 512 * 2;
  bf16_t* WhT = (bf16_t*)ws; ws += 128 * 512 * 2;
  bf16_t* WrT = (bf16_t*)ws; ws += 128 * 384 * 2;
  bf16_t* UrT = (bf16_t*)ws; ws += 128 * 128 * 2;
  bf16_t* WoT = (bf16_t*)ws; ws += 128 * 384 * 2;
  bf16_t* bzB  = (bf16_t*)ws; ws += 128 * 2;
  bf16_t* burB = (bf16_t*)ws; ws += 128 * 2;
  bf16_t* bhB  = (bf16_t*)ws; ws += 128 * 2;
  bf16_t* boB  = (bf16_t*)ws; ws += 128 * 2;
  int* aI    = (int*)ws; ws += (size_t)N_ * 6 * 4;
  int* bI    = (int*)ws; ws += (size_t)E_ * 6 * 4;
  int* flags = (int*)ws; ws += 16;

  // OUTPUT AS F32: out0 [N,128] then h [E,128]
  float* out0F = (float*)d_out;
  float* hOutF = out0F + (size_t)N_ * 128;
  bf16_t* NM   = G;   // alias: G dead before nm_gather

  const bf16_t* fmessH = (const bf16_t*)fmess;   // valid when input is bf16
  const float*  fmessF = (const float*)fmess;    // valid when input is f32
  const bf16_t* fnodeH = (const bf16_t*)fnode;
  const float*  fnodeF = (const float*)fnode;

  detect<<<1, 64, 0, stream>>>(fmess, bgraph, flags);
  prep<<<256, 256, 0, stream>>>(Wz, Wr, Ur, Wh, Wo, bz, bur, bh, bo, flags,
                                WzT, WhT, WrT, UrT, WoT, bzB, burB, bhB, boB);
  idx_cvt<<<1875, 256, 0, stream>>>(agraph, bgraph, aI, bI, flags);

  // Mr = fmess @ Wr + bur   (loop-invariant)
  mgemm<384, 0, 0><<<625, 512, 0, stream>>>(
      fmessH, fmessF, 384, 1, nullptr, nullptr, WrT, nullptr, 384, flags,
      burB, nullptr, nullptr, nullptr, nullptr, Mr, nullptr, E_);

  // Hoist: Pz = fmess@Wz1 + bz, Ph = fmess@Wh1 + bh (both f32, loop-invariant)
  // Fused depth-0 epilogue: h0 = sig(Pz)*tanh(Ph), row0 = 0.
  mgemm<384, 0, 3><<<625, 512, 0, stream>>>(
      fmessH, fmessF, 384, 1, nullptr, nullptr, WzT, WhT, 512, flags,
      bzB, bhB, nullptr, PzF, PhF, hP0, nullptr, E_);

  const bf16_t* src = hP0;
  bf16_t* dst = hP1;
  for (int d = 0; d < 2; ++d) {
    // G = h @ Ur
    mgemm<128, 0, 0><<<625, 512, 0, stream>>>(
        src, nullptr, 128, 0, nullptr, nullptr, UrT, nullptr, 128, flags,
        nullptr, nullptr, nullptr, nullptr, nullptr, G, nullptr, E_);

    depth_gather<<<5000, 256, 0, stream>>>(src, G, Mr, bI, S, T);

    // h' = (1-z)*S + z*tanh(Ph + T@Wh2),  z = sig(Pz + S@Wz2)
    mgemm<0, 128, 4><<<625, 512, 0, stream>>>(
        nullptr, nullptr, 0, 0, S, T, WzT + 384, WhT + 384, 512, flags,
        nullptr, nullptr, S, PzF, PhF, dst, (d == 1) ? hOutF : nullptr, E_);

    src = dst;
    dst = (d == 0) ? hP0 : hP1;
  }
  const bf16_t* hFinal = hP0;   // d=1: src was hP1, dst was hP0

  nm_gather<<<2500, 256, 0, stream>>>(hFinal, aI, NM);

  // out = relu(fnode@Wo1 + NM@Wo2 + bo), row0 = 0   -> f32
  mgemm<256, 128, 2><<<313, 512, 0, stream>>>(
      fnodeH, fnodeF, 256, 1, NM, nullptr, WoT, nullptr, 384, flags,
      boB, nullptr, nullptr, nullptr, nullptr, nullptr, out0F, N_);
}

// Round 5
// 540.106 us; speedup vs baseline: 1.1104x; 1.1104x over previous
//
#include <hip/hip_runtime.h>
#include <hip/hip_bf16.h>
#include <cstdint>
#include <cstddef>

typedef __bf16 bf16_t;
typedef __bf16 bf16x8 __attribute__((ext_vector_type(8)));
typedef __bf16 bf16x4 __attribute__((ext_vector_type(4)));
typedef float  floatx4 __attribute__((ext_vector_type(4)));

#define DEV static __device__ __forceinline__

DEV float sigm(float x) { return 1.f / (1.f + __expf(-x)); }

constexpr int E_ = 80000;   // edges
constexpr int N_ = 40000;   // nodes
// H = 128, IN = 384, NODE_FDIM = 256, MAX_NB = 6

// ---------------------------------------------------------------------------
// detect: classify input float width (bf16 vs f32) and index width (i32/i64).
// flags[0]=1 -> floats are f32; flags[1]=1 -> idx are i64.  (unchanged)
// ---------------------------------------------------------------------------
__global__ void detect(const void* fmess, const void* bgraph, int* flags) {
  if (threadIdx.x == 0 && blockIdx.x == 0) {
    const uint16_t* w = (const uint16_t*)fmess;
    int good = 0;
    for (int j = 0; j < 128; ++j) {
      uint16_t x = w[j];
      int e = (x >> 7) & 0xFF;
      if (x == 0 || x == 0x8000 || (e >= 100 && e <= 140)) ++good;
    }
    flags[0] = (good < 110) ? 1 : 0;
    const uint32_t* q = (const uint32_t*)bgraph;
    int zeros = 0;
    for (int j = 0; j < 128; ++j)
      if (q[2 * j + 1] == 0u) ++zeros;
    flags[1] = (zeros >= 120) ? 1 : 0;
  }
}

DEV float rdf(const void* p, size_t i, bool f32) {
  return f32 ? ((const float*)p)[i] : (float)((const bf16_t*)p)[i];
}

// ---------------------------------------------------------------------------
// prep: dtype-aware transposed weight copies (BT[n][k] = W[k][n]) + bf16 bias
// copies.  WzT/WhT [128,512], WrT/WoT [128,384], UrT [128,128].  (unchanged)
// ---------------------------------------------------------------------------
__launch_bounds__(256)
__global__ void prep(const void* Wz, const void* Wr, const void* Ur,
                     const void* Wh, const void* Wo,
                     const void* bz, const void* bur, const void* bh,
                     const void* bo, const int* flags,
                     bf16_t* WzT, bf16_t* WhT, bf16_t* WrT, bf16_t* UrT,
                     bf16_t* WoT, bf16_t* bzB, bf16_t* burB, bf16_t* bhB,
                     bf16_t* boB) {
  const bool f32 = flags[0] != 0;
  int i = blockIdx.x * blockDim.x + threadIdx.x;   // 65536 threads
  {  // 128 x 512
    int j = i >> 9, k = i & 511;
    WzT[i] = (bf16_t)rdf(Wz, (size_t)k * 128 + j, f32);
    WhT[i] = (bf16_t)rdf(Wh, (size_t)k * 128 + j, f32);
  }
  if (i < 128 * 384) {
    int j = i / 384, k = i % 384;
    WrT[i] = (bf16_t)rdf(Wr, (size_t)k * 128 + j, f32);
    WoT[i] = (bf16_t)rdf(Wo, (size_t)k * 128 + j, f32);
  }
  if (i < 128 * 128) {
    int j = i >> 7, k = i & 127;
    UrT[i] = (bf16_t)rdf(Ur, (size_t)k * 128 + j, f32);
  }
  if (i < 128) {
    bzB[i]  = (bf16_t)rdf(bz, i, f32);
    burB[i] = (bf16_t)rdf(bur, i, f32);
    bhB[i]  = (bf16_t)rdf(bh, i, f32);
    boB[i]  = (bf16_t)rdf(bo, i, f32);
  }
}

// ---------------------------------------------------------------------------
// idx_cvt: normalize agraph/bgraph to int32 ws copies.  (unchanged)
// ---------------------------------------------------------------------------
__launch_bounds__(256)
__global__ void idx_cvt(const void* ag, const void* bg, int* aI, int* bI,
                        const int* flags) {
  const bool i64 = flags[1] != 0;
  int i = blockIdx.x * blockDim.x + threadIdx.x;   // 480000 threads
  if (i < N_ * 6)
    aI[i] = i64 ? (int)((const long long*)ag)[i] : ((const int*)ag)[i];
  if (i < E_ * 6)
    bI[i] = i64 ? (int)((const long long*)bg)[i] : ((const int*)bg)[i];
}

// ---------------------------------------------------------------------------
// MFMA GEMM, LDS double-buffered (BM=128, BN=128, BK=32; 8 waves 2m x 4n;
// wave tile 64x32).  Slot-swizzle (2-way bank aliasing = free): slot s of
// row r holds global k-quad q = s ^ ((r>>1)&3); applied on the global source
// for global_load_lds (linear LDS dest), inverse on ds_read.
// f32 A inputs are converted in-register during staging.
//
// MODE 0: Cb = acc0 + bias0                     (single B; A0 over K0)
// MODE 2: Cf = relu(acc0 + bias0), row0=0       (A0 over K0 + A1a over K1)
// MODE 3: pz = acc0+bias0, ph = acc1+bias1 ; F0=pz, F1=ph (bf16);
//         Cb = sig(pz)*tanh(ph), row0=0        (dual B, shared A0 over K0)
// ---------------------------------------------------------------------------
DEV void gld16(const bf16_t* g, bf16_t* l) {
  __builtin_amdgcn_global_load_lds(
      (const __attribute__((address_space(1))) void*)g,
      (__attribute__((address_space(3))) void*)l, 16, 0, 0);
}

DEV floatx4 mfma16(bf16x8 a, bf16x8 b, floatx4 c) {
  return __builtin_amdgcn_mfma_f32_16x16x32_bf16(a, b, c, 0, 0, 0);
}

template <int K0, int K1, int MODE>
__launch_bounds__(512, 4)
__global__ void mgemm(const bf16_t* A0h, const float* A0f, int lda0, int a0dyn,
                      const bf16_t* A1a,
                      const bf16_t* Ba, const bf16_t* Bb, int ldb,
                      const int* flags,
                      const bf16_t* bias0, const bf16_t* bias1,
                      bf16_t* F0, bf16_t* F1,
                      bf16_t* Cb, float* Cf, int Mrows) {
  constexpr int NT0 = K0 / 32, NT1 = K1 / 32, NT = NT0 + NT1;
  constexpr bool DUALB = (MODE == 3);
  constexpr int NTILES = DUALB ? 3 : 2;
  // tile slots (x4096 elems): 0=A, 1=Ba, 2=Bb (DUALB)
  __shared__ bf16_t lds[2][NTILES * 128 * 32];

  const bool aF32 = a0dyn && (flags[0] != 0);

  const int tid  = threadIdx.x;
  const int w    = tid >> 6, lane = tid & 63;
  const int wm   = w >> 2, wn = w & 3;
  const int lr   = lane & 15, kg = lane >> 4;
  const int rowBase = blockIdx.x * 128;

  // staging lane map: each wave stages 16 rows/cols per tile
  const int rr = lane >> 2, sq = lane & 3;
  const int r  = w * 16 + rr;                   // tile row (A) / col (B)
  const int q  = sq ^ ((r >> 1) & 3);           // global k-quad for this slot
  const int ldsOff = w * 512;                   // elems; wave-uniform base
  int gRowA = rowBase + r;
  if (gRowA > Mrows - 1) gRowA = Mrows - 1;     // tail clamp

  floatx4 acc0[4][2] = {};
  floatx4 acc1[4][2] = {};

  auto stage = [&](int kt, int buf) {
    if (kt < NT0) {
      int kk = kt * 32 + q * 8;
      if (aF32) {
        const float* ap = A0f + (size_t)gRowA * lda0 + kk;
        floatx4 x0 = *(const floatx4*)ap;
        floatx4 x1 = *(const floatx4*)(ap + 4);
        bf16x8 o;
#pragma unroll
        for (int j = 0; j < 4; ++j) { o[j] = (bf16_t)x0[j]; o[4 + j] = (bf16_t)x1[j]; }
        *(bf16x8*)(&lds[buf][0] + ldsOff + lane * 8) = o;
      } else {
        gld16(A0h + (size_t)gRowA * lda0 + kk, &lds[buf][0] + ldsOff);
      }
    } else {
      int kk = (kt - NT0) * 32 + q * 8;
      gld16(A1a + (size_t)gRowA * K1 + kk, &lds[buf][0] + ldsOff);
    }
    gld16(Ba + (size_t)r * ldb + kt * 32 + q * 8, &lds[buf][4096] + ldsOff);
    if constexpr (DUALB)
      gld16(Bb + (size_t)r * ldb + kt * 32 + q * 8, &lds[buf][2 * 4096] + ldsOff);
  };

  auto compute = [&](int buf) {
    const bf16_t* L = lds[buf];
    bf16x8 b0[2], b1[2];
#pragma unroll
    for (int ni = 0; ni < 2; ++ni) {
      int c = wn * 32 + ni * 16 + lr;
      int s = kg ^ ((c >> 1) & 3);
      b0[ni] = *(const bf16x8*)(L + 4096 + c * 32 + s * 8);
      if constexpr (DUALB)
        b1[ni] = *(const bf16x8*)(L + 2 * 4096 + c * 32 + s * 8);
    }
#pragma unroll
    for (int mi = 0; mi < 4; ++mi) {
      int rA = wm * 64 + mi * 16 + lr;
      int s  = kg ^ ((rA >> 1) & 3);
      bf16x8 a0 = *(const bf16x8*)(L + rA * 32 + s * 8);
#pragma unroll
      for (int ni = 0; ni < 2; ++ni)
        acc0[mi][ni] = mfma16(a0, b0[ni], acc0[mi][ni]);
      if constexpr (DUALB) {
#pragma unroll
        for (int ni = 0; ni < 2; ++ni)
          acc1[mi][ni] = mfma16(a0, b1[ni], acc1[mi][ni]);
      }
    }
  };

  stage(0, 0);
  __syncthreads();
  int cur = 0;
#pragma unroll 1
  for (int kt = 0; kt < NT; ++kt) {
    if (kt + 1 < NT) stage(kt + 1, cur ^ 1);
    compute(cur);
    __syncthreads();
    cur ^= 1;
  }

#pragma unroll
  for (int mi = 0; mi < 4; ++mi) {
#pragma unroll
    for (int ni = 0; ni < 2; ++ni) {
      const int col = wn * 32 + ni * 16 + lr;
#pragma unroll
      for (int r4 = 0; r4 < 4; ++r4) {
        const int row = rowBase + wm * 64 + mi * 16 + kg * 4 + r4;
        if (row < Mrows) {
          const size_t o = (size_t)row * 128 + col;
          float x0 = acc0[mi][ni][r4];
          if constexpr (MODE == 0) {
            float v = x0 + (bias0 ? (float)bias0[col] : 0.f);
            Cb[o] = (bf16_t)v;
          } else if constexpr (MODE == 2) {
            float v = fmaxf(x0 + (float)bias0[col], 0.f);
            if (row == 0) v = 0.f;
            Cf[o] = v;
          } else {  // MODE 3
            float pz = x0 + (float)bias0[col];
            float ph = acc1[mi][ni][r4] + (float)bias1[col];
            F0[o] = (bf16_t)pz;
            F1[o] = (bf16_t)ph;
            float v = sigm(pz) * tanhf(ph);
            if (row == 0) v = 0.f;
            Cb[o] = (bf16_t)v;
          }
        }
      }
    }
  }
}

// ---------------------------------------------------------------------------
// gru_fused: one kernel per depth = gather + dual K=128 MFMA GEMM + GRU
// epilogue.  Block: 512 thr (8 waves, 2m x 4n), 128 edges x 128 cols.
// Phase 1: gather S = sum h_nei, T = sum sig(Mr + G_nei)*h_nei DIRECTLY into
//   swizzled LDS A-tiles Sl/Tl [4 ktiles][128][32] (same 2-way-free scheme).
// Phase 2: 4 k-steps: acc0 += S@Wz2, acc1 += T@Wh2 (B-frags register-
//   prefetched from L2; weights are 64KB, resident).
// Epilogue: z = sig(acc0 + Pz), ph = tanh(acc1 + Ph),
//   h' = (1-z)*S(LDS) + z*ph, row0=0 -> bf16 (+ optional f32).
// ---------------------------------------------------------------------------
__launch_bounds__(512, 4)
__global__ void gru_fused(const bf16_t* h, const bf16_t* G, const bf16_t* Mr,
                          const int* bgraph,
                          const bf16_t* PzB, const bf16_t* PhB,
                          const bf16_t* WzT, const bf16_t* WhT,  // [128][512]
                          bf16_t* hOut, float* hOutF) {
  __shared__ bf16_t Sl[4][128][32];
  __shared__ bf16_t Tl[4][128][32];

  const int tid  = threadIdx.x;
  const int w    = tid >> 6, lane = tid & 63;
  const int wm   = w >> 2, wn = w & 3;
  const int lr   = lane & 15, kg = lane >> 4;
  const int rowBase = blockIdx.x * 128;

  // --- B-frag prefetch for kt=0 (issues before gather; latency hidden) ---
  bf16x8 bzc[2], bhc[2];
#pragma unroll
  for (int ni = 0; ni < 2; ++ni) {
    int c = wn * 32 + ni * 16 + lr;
    bzc[ni] = *(const bf16x8*)(WzT + (size_t)c * 512 + 384 + kg * 8);
    bhc[ni] = *(const bf16x8*)(WhT + (size_t)c * 512 + 384 + kg * 8);
  }

  // --- Phase 1: gather into swizzled LDS ---
  const int c8 = (tid & 15) * 8;        // col group (const across units)
  const int ktw = c8 >> 5, qw = (c8 >> 3) & 3;
#pragma unroll 1
  for (int u = 0; u < 4; ++u) {
    int el = (tid >> 4) + u * 32;       // local edge 0..127
    int e  = rowBase + el;
    bf16x8 mr = *(const bf16x8*)(Mr + (size_t)e * 128 + c8);
    float mrf[8];
#pragma unroll
    for (int j = 0; j < 8; ++j) mrf[j] = (float)mr[j];
    float sa[8] = {}, ta[8] = {};
    const int* bg = bgraph + (size_t)e * 6;
#pragma unroll
    for (int n = 0; n < 6; ++n) {
      int idx = bg[n];
      bf16x8 h8 = *(const bf16x8*)(h + (size_t)idx * 128 + c8);
      bf16x8 g8 = *(const bf16x8*)(G + (size_t)idx * 128 + c8);
#pragma unroll
      for (int j = 0; j < 8; ++j) {
        float hv = (float)h8[j];
        float rg = sigm(mrf[j] + (float)g8[j]);
        sa[j] += hv;
        ta[j] += rg * hv;
      }
    }
    bf16x8 sv, tv;
#pragma unroll
    for (int j = 0; j < 8; ++j) { sv[j] = (bf16_t)sa[j]; tv[j] = (bf16_t)ta[j]; }
    int slot = qw ^ ((el >> 1) & 3);
    *(bf16x8*)&Sl[ktw][el][slot * 8] = sv;
    *(bf16x8*)&Tl[ktw][el][slot * 8] = tv;
  }
  __syncthreads();

  // --- Phase 2: 4 k-steps of dual MFMA ---
  floatx4 acc0[4][2] = {};
  floatx4 acc1[4][2] = {};
#pragma unroll
  for (int kt = 0; kt < 4; ++kt) {
    bf16x8 bzn[2], bhn[2];
    if (kt < 3) {
#pragma unroll
      for (int ni = 0; ni < 2; ++ni) {
        int c = wn * 32 + ni * 16 + lr;
        bzn[ni] = *(const bf16x8*)(WzT + (size_t)c * 512 + 384 + (kt + 1) * 32 + kg * 8);
        bhn[ni] = *(const bf16x8*)(WhT + (size_t)c * 512 + 384 + (kt + 1) * 32 + kg * 8);
      }
    }
#pragma unroll
    for (int mi = 0; mi < 4; ++mi) {
      int rA = wm * 64 + mi * 16 + lr;
      int s  = kg ^ ((rA >> 1) & 3);
      bf16x8 aS = *(const bf16x8*)&Sl[kt][rA][s * 8];
      bf16x8 aT = *(const bf16x8*)&Tl[kt][rA][s * 8];
#pragma unroll
      for (int ni = 0; ni < 2; ++ni) {
        acc0[mi][ni] = mfma16(aS, bzc[ni], acc0[mi][ni]);
        acc1[mi][ni] = mfma16(aT, bhc[ni], acc1[mi][ni]);
      }
    }
    if (kt < 3) {
#pragma unroll
      for (int ni = 0; ni < 2; ++ni) { bzc[ni] = bzn[ni]; bhc[ni] = bhn[ni]; }
    }
  }

  // --- Epilogue ---
#pragma unroll
  for (int mi = 0; mi < 4; ++mi) {
#pragma unroll
    for (int ni = 0; ni < 2; ++ni) {
      const int col = wn * 32 + ni * 16 + lr;
      const int ktc = col >> 5, qc = (col >> 3) & 3;
#pragma unroll
      for (int r4 = 0; r4 < 4; ++r4) {
        const int elr = wm * 64 + mi * 16 + kg * 4 + r4;
        const int row = rowBase + elr;
        const size_t o = (size_t)row * 128 + col;
        float pz = acc0[mi][ni][r4] + (float)PzB[o];
        float ph = acc1[mi][ni][r4] + (float)PhB[o];
        float z  = sigm(pz);
        float th = tanhf(ph);
        int  sl  = qc ^ ((elr >> 1) & 3);
        float sI = (float)Sl[ktc][elr][sl * 8 + (col & 7)];
        float v  = (1.f - z) * sI + z * th;
        if (row == 0) v = 0.f;
        hOut[o] = (bf16_t)v;
        if (hOutF) hOutF[o] = v;
      }
    }
  }
}

// ---------------------------------------------------------------------------
// Node gather: NM[v] = sum_n h[agraph[v,n]]   (unchanged)
// ---------------------------------------------------------------------------
__launch_bounds__(256)
__global__ void nm_gather(const bf16_t* h, const int* agraph, bf16_t* NM) {
  int t = threadIdx.x;
  int v = blockIdx.x * 16 + (t >> 4);
  int c8 = (t & 15) * 8;
  float sa[8] = {};
  const int* ag = agraph + (size_t)v * 6;
#pragma unroll
  for (int n = 0; n < 6; ++n) {
    int idx = ag[n];
    bf16x8 h8 = *(const bf16x8*)(h + (size_t)idx * 128 + c8);
#pragma unroll
    for (int j = 0; j < 8; ++j) sa[j] += (float)h8[j];
  }
  bf16x8 o;
#pragma unroll
  for (int j = 0; j < 8; ++j) o[j] = (bf16_t)sa[j];
  *(bf16x8*)(NM + (size_t)v * 128 + c8) = o;
}

// ---------------------------------------------------------------------------
extern "C" void kernel_launch(void* const* d_in, const int* in_sizes, int n_in,
                              void* d_out, int out_size, void* d_ws, size_t ws_size,
                              hipStream_t stream) {
  const void* fnode  = d_in[0];
  const void* fmess  = d_in[1];
  const void* agraph = d_in[2];
  const void* bgraph = d_in[3];
  const void* Wz  = d_in[4];
  const void* bz  = d_in[5];
  const void* Wr  = d_in[6];
  const void* Ur  = d_in[7];
  const void* bur = d_in[8];
  const void* Wh  = d_in[9];
  const void* bh  = d_in[10];
  const void* Wo  = d_in[11];
  const void* bo  = d_in[12];

  // workspace: 7 x [E,128] bf16 + weights + idx copies
  char* ws = (char*)d_ws;
  bf16_t* Mr  = (bf16_t*)ws; ws += (size_t)E_ * 128 * 2;  // fmess@Wr + bur
  bf16_t* G   = (bf16_t*)ws; ws += (size_t)E_ * 128 * 2;  // h@Ur; later NM
  bf16_t* hP0 = (bf16_t*)ws; ws += (size_t)E_ * 128 * 2;  // h ping
  bf16_t* hP1 = (bf16_t*)ws; ws += (size_t)E_ * 128 * 2;  // h pong
  bf16_t* PzB = (bf16_t*)ws; ws += (size_t)E_ * 128 * 2;  // fmess@Wz1 + bz
  bf16_t* PhB = (bf16_t*)ws; ws += (size_t)E_ * 128 * 2;  // fmess@Wh1 + bh
  bf16_t* WzT = (bf16_t*)ws; ws += 128 * 512 * 2;
  bf16_t* WhT = (bf16_t*)ws; ws += 128 * 512 * 2;
  bf16_t* WrT = (bf16_t*)ws; ws += 128 * 384 * 2;
  bf16_t* UrT = (bf16_t*)ws; ws += 128 * 128 * 2;
  bf16_t* WoT = (bf16_t*)ws; ws += 128 * 384 * 2;
  bf16_t* bzB  = (bf16_t*)ws; ws += 128 * 2;
  bf16_t* burB = (bf16_t*)ws; ws += 128 * 2;
  bf16_t* bhB  = (bf16_t*)ws; ws += 128 * 2;
  bf16_t* boB  = (bf16_t*)ws; ws += 128 * 2;
  int* aI    = (int*)ws; ws += (size_t)N_ * 6 * 4;
  int* bI    = (int*)ws; ws += (size_t)E_ * 6 * 4;
  int* flags = (int*)ws; ws += 16;

  // OUTPUT AS F32: out0 [N,128] then h [E,128]
  float* out0F = (float*)d_out;
  float* hOutF = out0F + (size_t)N_ * 128;
  bf16_t* NM   = G;   // alias: G dead before nm_gather

  const bf16_t* fmessH = (const bf16_t*)fmess;   // valid when input is bf16
  const float*  fmessF = (const float*)fmess;    // valid when input is f32
  const bf16_t* fnodeH = (const bf16_t*)fnode;
  const float*  fnodeF = (const float*)fnode;

  detect<<<1, 64, 0, stream>>>(fmess, bgraph, flags);
  prep<<<256, 256, 0, stream>>>(Wz, Wr, Ur, Wh, Wo, bz, bur, bh, bo, flags,
                                WzT, WhT, WrT, UrT, WoT, bzB, burB, bhB, boB);
  idx_cvt<<<1875, 256, 0, stream>>>(agraph, bgraph, aI, bI, flags);

  // Mr = fmess @ Wr + bur   (loop-invariant)
  mgemm<384, 0, 0><<<625, 512, 0, stream>>>(
      fmessH, fmessF, 384, 1, nullptr, WrT, nullptr, 384, flags,
      burB, nullptr, nullptr, nullptr, Mr, nullptr, E_);

  // Hoist: Pz = fmess@Wz1 + bz, Ph = fmess@Wh1 + bh (bf16, loop-invariant)
  // Fused depth-0 epilogue: h0 = sig(Pz)*tanh(Ph), row0 = 0.
  mgemm<384, 0, 3><<<625, 512, 0, stream>>>(
      fmessH, fmessF, 384, 1, nullptr, WzT, WhT, 512, flags,
      bzB, bhB, PzB, PhB, hP0, nullptr, E_);

  const bf16_t* src = hP0;
  bf16_t* dst = hP1;
  for (int d = 0; d < 2; ++d) {
    // G = h @ Ur
    mgemm<128, 0, 0><<<625, 512, 0, stream>>>(
        src, nullptr, 128, 0, nullptr, UrT, nullptr, 128, flags,
        nullptr, nullptr, nullptr, nullptr, G, nullptr, E_);

    // fused: gather(S,T) + h' = (1-z)*S + z*tanh(Ph + T@Wh2), z = sig(Pz + S@Wz2)
    gru_fused<<<625, 512, 0, stream>>>(
        src, G, Mr, bI, PzB, PhB, WzT, WhT, dst,
        (d == 1) ? hOutF : nullptr);

    src = dst;
    dst = (d == 0) ? hP0 : hP1;
  }
  const bf16_t* hFinal = hP0;   // d=1: src was hP1, dst was hP0

  nm_gather<<<2500, 256, 0, stream>>>(hFinal, aI, NM);

  // out = relu(fnode@Wo1 + NM@Wo2 + bo), row0 = 0   -> f32
  mgemm<256, 128, 2><<<313, 512, 0, stream>>>(
      fnodeH, fnodeF, 256, 1, NM, WoT, nullptr, 384, flags,
      boB, nullptr, nullptr, nullptr, nullptr, out0F, N_);
}

// Round 6
// 496.108 us; speedup vs baseline: 1.2088x; 1.0887x over previous
//
#include <hip/hip_runtime.h>
#include <hip/hip_bf16.h>
#include <cstdint>
#include <cstddef>

typedef __bf16 bf16_t;
typedef __bf16 bf16x8 __attribute__((ext_vector_type(8)));
typedef __bf16 bf16x4 __attribute__((ext_vector_type(4)));
typedef float  floatx4 __attribute__((ext_vector_type(4)));

#define DEV static __device__ __forceinline__

DEV float sigm(float x) { return 1.f / (1.f + __expf(-x)); }

constexpr int E_ = 80000;   // edges
constexpr int N_ = 40000;   // nodes
// H = 128, IN = 384, NODE_FDIM = 256, MAX_NB = 6

// ---------------------------------------------------------------------------
// detect: classify input float width (bf16 vs f32) and index width (i32/i64).
// flags[0]=1 -> floats are f32; flags[1]=1 -> idx are i64.  (unchanged)
// ---------------------------------------------------------------------------
__global__ void detect(const void* fmess, const void* bgraph, int* flags) {
  if (threadIdx.x == 0 && blockIdx.x == 0) {
    const uint16_t* w = (const uint16_t*)fmess;
    int good = 0;
    for (int j = 0; j < 128; ++j) {
      uint16_t x = w[j];
      int e = (x >> 7) & 0xFF;
      if (x == 0 || x == 0x8000 || (e >= 100 && e <= 140)) ++good;
    }
    flags[0] = (good < 110) ? 1 : 0;
    const uint32_t* q = (const uint32_t*)bgraph;
    int zeros = 0;
    for (int j = 0; j < 128; ++j)
      if (q[2 * j + 1] == 0u) ++zeros;
    flags[1] = (zeros >= 120) ? 1 : 0;
  }
}

DEV float rdf(const void* p, size_t i, bool f32) {
  return f32 ? ((const float*)p)[i] : (float)((const bf16_t*)p)[i];
}

// ---------------------------------------------------------------------------
// prep: dtype-aware transposed weight copies (BT[n][k] = W[k][n]) + bf16 bias
// copies.  WzT/WhT [128,512], WrT/WoT [128,384], UrT [128,128].  (unchanged)
// ---------------------------------------------------------------------------
__launch_bounds__(256)
__global__ void prep(const void* Wz, const void* Wr, const void* Ur,
                     const void* Wh, const void* Wo,
                     const void* bz, const void* bur, const void* bh,
                     const void* bo, const int* flags,
                     bf16_t* WzT, bf16_t* WhT, bf16_t* WrT, bf16_t* UrT,
                     bf16_t* WoT, bf16_t* bzB, bf16_t* burB, bf16_t* bhB,
                     bf16_t* boB) {
  const bool f32 = flags[0] != 0;
  int i = blockIdx.x * blockDim.x + threadIdx.x;   // 65536 threads
  {  // 128 x 512
    int j = i >> 9, k = i & 511;
    WzT[i] = (bf16_t)rdf(Wz, (size_t)k * 128 + j, f32);
    WhT[i] = (bf16_t)rdf(Wh, (size_t)k * 128 + j, f32);
  }
  if (i < 128 * 384) {
    int j = i / 384, k = i % 384;
    WrT[i] = (bf16_t)rdf(Wr, (size_t)k * 128 + j, f32);
    WoT[i] = (bf16_t)rdf(Wo, (size_t)k * 128 + j, f32);
  }
  if (i < 128 * 128) {
    int j = i >> 7, k = i & 127;
    UrT[i] = (bf16_t)rdf(Ur, (size_t)k * 128 + j, f32);
  }
  if (i < 128) {
    bzB[i]  = (bf16_t)rdf(bz, i, f32);
    burB[i] = (bf16_t)rdf(bur, i, f32);
    bhB[i]  = (bf16_t)rdf(bh, i, f32);
    boB[i]  = (bf16_t)rdf(bo, i, f32);
  }
}

// ---------------------------------------------------------------------------
// idx_cvt: normalize agraph/bgraph to int32 ws copies.  (unchanged)
// ---------------------------------------------------------------------------
__launch_bounds__(256)
__global__ void idx_cvt(const void* ag, const void* bg, int* aI, int* bI,
                        const int* flags) {
  const bool i64 = flags[1] != 0;
  int i = blockIdx.x * blockDim.x + threadIdx.x;   // 480000 threads
  if (i < N_ * 6)
    aI[i] = i64 ? (int)((const long long*)ag)[i] : ((const int*)ag)[i];
  if (i < E_ * 6)
    bI[i] = i64 ? (int)((const long long*)bg)[i] : ((const int*)bg)[i];
}

// ---------------------------------------------------------------------------
// MFMA GEMM, LDS double-buffered (BM=128, BN=128, BK=32; 8 waves 2m x 4n;
// wave tile 64x32).  Slot-swizzle (2-way bank aliasing = free): slot s of
// row r holds global k-quad q = s ^ ((r>>1)&3); applied on the global source
// for global_load_lds (linear LDS dest), inverse on ds_read.
// f32 A inputs are converted in-register during staging.
//
// MODE 0: Cb = acc0 + bias0                     (single B; A0 over K0)
// MODE 2: Cf = relu(acc0 + bias0), row0=0       (A0 over K0 + A1a over K1)
// MODE 3: pz = acc0+bias0, ph = acc1+bias1 ; F0=pz, F1=ph (bf16);
//         Cb = sig(pz)*tanh(ph), row0=0        (dual B, shared A0 over K0)
// Cb uses stride ldcB (to support packed HG rows); Cf/F0/F1 use stride 128.
// ---------------------------------------------------------------------------
DEV void gld16(const bf16_t* g, bf16_t* l) {
  __builtin_amdgcn_global_load_lds(
      (const __attribute__((address_space(1))) void*)g,
      (__attribute__((address_space(3))) void*)l, 16, 0, 0);
}

DEV floatx4 mfma16(bf16x8 a, bf16x8 b, floatx4 c) {
  return __builtin_amdgcn_mfma_f32_16x16x32_bf16(a, b, c, 0, 0, 0);
}

template <int K0, int K1, int MODE>
__launch_bounds__(512, 4)
__global__ void mgemm(const bf16_t* A0h, const float* A0f, int lda0, int a0dyn,
                      const bf16_t* A1a,
                      const bf16_t* Ba, const bf16_t* Bb, int ldb,
                      const int* flags,
                      const bf16_t* bias0, const bf16_t* bias1,
                      bf16_t* F0, bf16_t* F1,
                      bf16_t* Cb, int ldcB, float* Cf, int Mrows) {
  constexpr int NT0 = K0 / 32, NT1 = K1 / 32, NT = NT0 + NT1;
  constexpr bool DUALB = (MODE == 3);
  constexpr int NTILES = DUALB ? 3 : 2;
  // tile slots (x4096 elems): 0=A, 1=Ba, 2=Bb (DUALB)
  __shared__ bf16_t lds[2][NTILES * 128 * 32];

  const bool aF32 = a0dyn && (flags[0] != 0);

  const int tid  = threadIdx.x;
  const int w    = tid >> 6, lane = tid & 63;
  const int wm   = w >> 2, wn = w & 3;
  const int lr   = lane & 15, kg = lane >> 4;
  const int rowBase = blockIdx.x * 128;

  // staging lane map: each wave stages 16 rows/cols per tile
  const int rr = lane >> 2, sq = lane & 3;
  const int r  = w * 16 + rr;                   // tile row (A) / col (B)
  const int q  = sq ^ ((r >> 1) & 3);           // global k-quad for this slot
  const int ldsOff = w * 512;                   // elems; wave-uniform base
  int gRowA = rowBase + r;
  if (gRowA > Mrows - 1) gRowA = Mrows - 1;     // tail clamp

  floatx4 acc0[4][2] = {};
  floatx4 acc1[4][2] = {};

  auto stage = [&](int kt, int buf) {
    if (kt < NT0) {
      int kk = kt * 32 + q * 8;
      if (aF32) {
        const float* ap = A0f + (size_t)gRowA * lda0 + kk;
        floatx4 x0 = *(const floatx4*)ap;
        floatx4 x1 = *(const floatx4*)(ap + 4);
        bf16x8 o;
#pragma unroll
        for (int j = 0; j < 4; ++j) { o[j] = (bf16_t)x0[j]; o[4 + j] = (bf16_t)x1[j]; }
        *(bf16x8*)(&lds[buf][0] + ldsOff + lane * 8) = o;
      } else {
        gld16(A0h + (size_t)gRowA * lda0 + kk, &lds[buf][0] + ldsOff);
      }
    } else {
      int kk = (kt - NT0) * 32 + q * 8;
      gld16(A1a + (size_t)gRowA * K1 + kk, &lds[buf][0] + ldsOff);
    }
    gld16(Ba + (size_t)r * ldb + kt * 32 + q * 8, &lds[buf][4096] + ldsOff);
    if constexpr (DUALB)
      gld16(Bb + (size_t)r * ldb + kt * 32 + q * 8, &lds[buf][2 * 4096] + ldsOff);
  };

  auto compute = [&](int buf) {
    const bf16_t* L = lds[buf];
    bf16x8 b0[2], b1[2];
#pragma unroll
    for (int ni = 0; ni < 2; ++ni) {
      int c = wn * 32 + ni * 16 + lr;
      int s = kg ^ ((c >> 1) & 3);
      b0[ni] = *(const bf16x8*)(L + 4096 + c * 32 + s * 8);
      if constexpr (DUALB)
        b1[ni] = *(const bf16x8*)(L + 2 * 4096 + c * 32 + s * 8);
    }
#pragma unroll
    for (int mi = 0; mi < 4; ++mi) {
      int rA = wm * 64 + mi * 16 + lr;
      int s  = kg ^ ((rA >> 1) & 3);
      bf16x8 a0 = *(const bf16x8*)(L + rA * 32 + s * 8);
#pragma unroll
      for (int ni = 0; ni < 2; ++ni)
        acc0[mi][ni] = mfma16(a0, b0[ni], acc0[mi][ni]);
      if constexpr (DUALB) {
#pragma unroll
        for (int ni = 0; ni < 2; ++ni)
          acc1[mi][ni] = mfma16(a0, b1[ni], acc1[mi][ni]);
      }
    }
  };

  stage(0, 0);
  __syncthreads();
  int cur = 0;
#pragma unroll 1
  for (int kt = 0; kt < NT; ++kt) {
    if (kt + 1 < NT) stage(kt + 1, cur ^ 1);
    compute(cur);
    __syncthreads();
    cur ^= 1;
  }

#pragma unroll
  for (int mi = 0; mi < 4; ++mi) {
#pragma unroll
    for (int ni = 0; ni < 2; ++ni) {
      const int col = wn * 32 + ni * 16 + lr;
#pragma unroll
      for (int r4 = 0; r4 < 4; ++r4) {
        const int row = rowBase + wm * 64 + mi * 16 + kg * 4 + r4;
        if (row < Mrows) {
          const size_t oC = (size_t)row * ldcB + col;
          const size_t oF = (size_t)row * 128 + col;
          float x0 = acc0[mi][ni][r4];
          if constexpr (MODE == 0) {
            float v = x0 + (bias0 ? (float)bias0[col] : 0.f);
            Cb[oC] = (bf16_t)v;
          } else if constexpr (MODE == 2) {
            float v = fmaxf(x0 + (float)bias0[col], 0.f);
            if (row == 0) v = 0.f;
            Cf[oF] = v;
          } else {  // MODE 3
            float pz = x0 + (float)bias0[col];
            float ph = acc1[mi][ni][r4] + (float)bias1[col];
            F0[oF] = (bf16_t)pz;
            F1[oF] = (bf16_t)ph;
            float v = sigm(pz) * tanhf(ph);
            if (row == 0) v = 0.f;
            Cb[oC] = (bf16_t)v;
          }
        }
      }
    }
  }
}

// ---------------------------------------------------------------------------
// gru_fused v2: gather + dual K=128 MFMA + GRU epilogue.
// Block: 256 thr (4 waves, 1m x 4n), 32 edges x 128 cols; LDS 16 KB ->
// high occupancy (launch_bounds(256,5): <=102 VGPR, ~20 waves/CU).
// h and G are PACKED in HG[e][256] (h = cols 0-127, G = 128-255): each
// neighbor gather touches one 512B segment instead of two 256B ones.
// Phase 1: u=0..1 (unrolled): 12 16B loads in flight per edge; S,T written
//   into swizzled LDS A-tiles Sl/Tl[4][32][32] (slot s = q ^ ((el>>1)&3)).
// Phase 2: 4 k-steps dual MFMA vs Wz2/Wh2 (B-frags reg-prefetched from L2).
// Epilogue: z = sig(acc0+Pz), ph = tanh(acc1+Ph), h' = (1-z)*S(LDS) + z*ph,
//   row0=0 -> hOut (stride 256, HG.h half) + optional f32.
// ---------------------------------------------------------------------------
__launch_bounds__(256, 5)
__global__ void gru_fused(const bf16_t* HG, const bf16_t* Mr,
                          const int* bgraph,
                          const bf16_t* PzB, const bf16_t* PhB,
                          const bf16_t* WzT, const bf16_t* WhT,  // [128][512]
                          bf16_t* hOut, float* hOutF) {
  __shared__ bf16_t Sl[4][32][32];
  __shared__ bf16_t Tl[4][32][32];

  const int tid  = threadIdx.x;
  const int w    = tid >> 6, lane = tid & 63;
  const int lr   = lane & 15, kg = lane >> 4;
  const int rowBase = blockIdx.x * 32;

  // --- Phase 1: gather into swizzled LDS (2 edges/thread, unrolled) ---
  const int c8 = (tid & 15) * 8;        // col group
  const int ktw = c8 >> 5, qw = (c8 >> 3) & 3;
#pragma unroll
  for (int u = 0; u < 2; ++u) {
    int el = (tid >> 4) + u * 16;       // local edge 0..31
    int e  = rowBase + el;
    const int* bg = bgraph + (size_t)e * 6;
    int idx[6];
#pragma unroll
    for (int n = 0; n < 6; ++n) idx[n] = bg[n];
    bf16x8 h8[6], g8[6];
#pragma unroll
    for (int n = 0; n < 6; ++n) {
      const bf16_t* p = HG + (size_t)idx[n] * 256 + c8;
      h8[n] = *(const bf16x8*)p;
      g8[n] = *(const bf16x8*)(p + 128);
    }
    bf16x8 mr = *(const bf16x8*)(Mr + (size_t)e * 128 + c8);
    float mrf[8];
#pragma unroll
    for (int j = 0; j < 8; ++j) mrf[j] = (float)mr[j];
    float sa[8] = {}, ta[8] = {};
#pragma unroll
    for (int n = 0; n < 6; ++n) {
#pragma unroll
      for (int j = 0; j < 8; ++j) {
        float hv = (float)h8[n][j];
        float rg = sigm(mrf[j] + (float)g8[n][j]);
        sa[j] += hv;
        ta[j] += rg * hv;
      }
    }
    bf16x8 sv, tv;
#pragma unroll
    for (int j = 0; j < 8; ++j) { sv[j] = (bf16_t)sa[j]; tv[j] = (bf16_t)ta[j]; }
    int slot = qw ^ ((el >> 1) & 3);
    *(bf16x8*)&Sl[ktw][el][slot * 8] = sv;
    *(bf16x8*)&Tl[ktw][el][slot * 8] = tv;
  }

  // --- B-frag prefetch for kt=0 (after gather: caps VGPR; overlaps other
  //     waves' gather) ---
  bf16x8 bzc[2], bhc[2];
#pragma unroll
  for (int ni = 0; ni < 2; ++ni) {
    int c = w * 32 + ni * 16 + lr;
    bzc[ni] = *(const bf16x8*)(WzT + (size_t)c * 512 + 384 + kg * 8);
    bhc[ni] = *(const bf16x8*)(WhT + (size_t)c * 512 + 384 + kg * 8);
  }
  __syncthreads();

  // --- Phase 2: 4 k-steps of dual MFMA (wave tile 32x32) ---
  floatx4 acc0[2][2] = {};
  floatx4 acc1[2][2] = {};
#pragma unroll
  for (int kt = 0; kt < 4; ++kt) {
    bf16x8 bzn[2], bhn[2];
    if (kt < 3) {
#pragma unroll
      for (int ni = 0; ni < 2; ++ni) {
        int c = w * 32 + ni * 16 + lr;
        bzn[ni] = *(const bf16x8*)(WzT + (size_t)c * 512 + 384 + (kt + 1) * 32 + kg * 8);
        bhn[ni] = *(const bf16x8*)(WhT + (size_t)c * 512 + 384 + (kt + 1) * 32 + kg * 8);
      }
    }
#pragma unroll
    for (int mi = 0; mi < 2; ++mi) {
      int rA = mi * 16 + lr;
      int s  = kg ^ ((rA >> 1) & 3);
      bf16x8 aS = *(const bf16x8*)&Sl[kt][rA][s * 8];
      bf16x8 aT = *(const bf16x8*)&Tl[kt][rA][s * 8];
#pragma unroll
      for (int ni = 0; ni < 2; ++ni) {
        acc0[mi][ni] = mfma16(aS, bzc[ni], acc0[mi][ni]);
        acc1[mi][ni] = mfma16(aT, bhc[ni], acc1[mi][ni]);
      }
    }
    if (kt < 3) {
#pragma unroll
      for (int ni = 0; ni < 2; ++ni) { bzc[ni] = bzn[ni]; bhc[ni] = bhn[ni]; }
    }
  }

  // --- Epilogue ---
#pragma unroll
  for (int mi = 0; mi < 2; ++mi) {
#pragma unroll
    for (int ni = 0; ni < 2; ++ni) {
      const int col = w * 32 + ni * 16 + lr;
      const int ktc = col >> 5, qc = (col >> 3) & 3;
#pragma unroll
      for (int r4 = 0; r4 < 4; ++r4) {
        const int elr = mi * 16 + kg * 4 + r4;
        const int row = rowBase + elr;
        const size_t oF = (size_t)row * 128 + col;
        float pz = acc0[mi][ni][r4] + (float)PzB[oF];
        float ph = acc1[mi][ni][r4] + (float)PhB[oF];
        float z  = sigm(pz);
        float th = tanhf(ph);
        int  sl  = qc ^ ((elr >> 1) & 3);
        float sI = (float)Sl[ktc][elr][sl * 8 + (col & 7)];
        float v  = (1.f - z) * sI + z * th;
        if (row == 0) v = 0.f;
        hOut[(size_t)row * 256 + col] = (bf16_t)v;
        if (hOutF) hOutF[oF] = v;
      }
    }
  }
}

// ---------------------------------------------------------------------------
// Node gather: NM[v] = sum_n h[agraph[v,n]]; h rows have stride 256 (HG.h)
// ---------------------------------------------------------------------------
__launch_bounds__(256)
__global__ void nm_gather(const bf16_t* HG, const int* agraph, bf16_t* NM) {
  int t = threadIdx.x;
  int v = blockIdx.x * 16 + (t >> 4);
  int c8 = (t & 15) * 8;
  float sa[8] = {};
  const int* ag = agraph + (size_t)v * 6;
  int idx[6];
#pragma unroll
  for (int n = 0; n < 6; ++n) idx[n] = ag[n];
#pragma unroll
  for (int n = 0; n < 6; ++n) {
    bf16x8 h8 = *(const bf16x8*)(HG + (size_t)idx[n] * 256 + c8);
#pragma unroll
    for (int j = 0; j < 8; ++j) sa[j] += (float)h8[j];
  }
  bf16x8 o;
#pragma unroll
  for (int j = 0; j < 8; ++j) o[j] = (bf16_t)sa[j];
  *(bf16x8*)(NM + (size_t)v * 128 + c8) = o;
}

// ---------------------------------------------------------------------------
extern "C" void kernel_launch(void* const* d_in, const int* in_sizes, int n_in,
                              void* d_out, int out_size, void* d_ws, size_t ws_size,
                              hipStream_t stream) {
  const void* fnode  = d_in[0];
  const void* fmess  = d_in[1];
  const void* agraph = d_in[2];
  const void* bgraph = d_in[3];
  const void* Wz  = d_in[4];
  const void* bz  = d_in[5];
  const void* Wr  = d_in[6];
  const void* Ur  = d_in[7];
  const void* bur = d_in[8];
  const void* Wh  = d_in[9];
  const void* bh  = d_in[10];
  const void* Wo  = d_in[11];
  const void* bo  = d_in[12];

  // workspace (~150 MB): 2 x HG [E,256] bf16 + 3 x [E,128] bf16 + weights + idx
  char* ws = (char*)d_ws;
  bf16_t* HGa = (bf16_t*)ws; ws += (size_t)E_ * 256 * 2;  // packed h||G ping
  bf16_t* HGb = (bf16_t*)ws; ws += (size_t)E_ * 256 * 2;  // packed h||G pong
  bf16_t* Mr  = (bf16_t*)ws; ws += (size_t)E_ * 128 * 2;  // fmess@Wr + bur
  bf16_t* PzB = (bf16_t*)ws; ws += (size_t)E_ * 128 * 2;  // fmess@Wz1 + bz
  bf16_t* PhB = (bf16_t*)ws; ws += (size_t)E_ * 128 * 2;  // fmess@Wh1 + bh
  bf16_t* WzT = (bf16_t*)ws; ws += 128 * 512 * 2;
  bf16_t* WhT = (bf16_t*)ws; ws += 128 * 512 * 2;
  bf16_t* WrT = (bf16_t*)ws; ws += 128 * 384 * 2;
  bf16_t* UrT = (bf16_t*)ws; ws += 128 * 128 * 2;
  bf16_t* WoT = (bf16_t*)ws; ws += 128 * 384 * 2;
  bf16_t* bzB  = (bf16_t*)ws; ws += 128 * 2;
  bf16_t* burB = (bf16_t*)ws; ws += 128 * 2;
  bf16_t* bhB  = (bf16_t*)ws; ws += 128 * 2;
  bf16_t* boB  = (bf16_t*)ws; ws += 128 * 2;
  int* aI    = (int*)ws; ws += (size_t)N_ * 6 * 4;
  int* bI    = (int*)ws; ws += (size_t)E_ * 6 * 4;
  int* flags = (int*)ws; ws += 16;

  // OUTPUT AS F32: out0 [N,128] then h [E,128]
  float* out0F = (float*)d_out;
  float* hOutF = out0F + (size_t)N_ * 128;
  bf16_t* NM   = HGb;   // alias: HGb dead before nm_gather

  const bf16_t* fmessH = (const bf16_t*)fmess;   // valid when input is bf16
  const float*  fmessF = (const float*)fmess;    // valid when input is f32
  const bf16_t* fnodeH = (const bf16_t*)fnode;
  const float*  fnodeF = (const float*)fnode;

  detect<<<1, 64, 0, stream>>>(fmess, bgraph, flags);
  prep<<<256, 256, 0, stream>>>(Wz, Wr, Ur, Wh, Wo, bz, bur, bh, bo, flags,
                                WzT, WhT, WrT, UrT, WoT, bzB, burB, bhB, boB);
  idx_cvt<<<1875, 256, 0, stream>>>(agraph, bgraph, aI, bI, flags);

  // Mr = fmess @ Wr + bur   (loop-invariant)
  mgemm<384, 0, 0><<<625, 512, 0, stream>>>(
      fmessH, fmessF, 384, 1, nullptr, WrT, nullptr, 384, flags,
      burB, nullptr, nullptr, nullptr, Mr, 128, nullptr, E_);

  // Hoist: Pz = fmess@Wz1 + bz, Ph = fmess@Wh1 + bh (bf16, loop-invariant)
  // Fused depth-0 epilogue: h0 = sig(Pz)*tanh(Ph), row0 = 0 -> HGa.h
  mgemm<384, 0, 3><<<625, 512, 0, stream>>>(
      fmessH, fmessF, 384, 1, nullptr, WzT, WhT, 512, flags,
      bzB, bhB, PzB, PhB, HGa, 256, nullptr, E_);

  const bf16_t* src = HGa;
  bf16_t* dst = HGb;
  for (int d = 0; d < 2; ++d) {
    // G = h @ Ur  -> packed into src[.][128:256]
    mgemm<128, 0, 0><<<625, 512, 0, stream>>>(
        src, nullptr, 256, 0, nullptr, UrT, nullptr, 128, flags,
        nullptr, nullptr, nullptr, nullptr, (bf16_t*)src + 128, 256, nullptr, E_);

    // fused: gather(S,T) + h' = (1-z)*S + z*tanh(Ph + T@Wh2), z = sig(Pz + S@Wz2)
    gru_fused<<<2500, 256, 0, stream>>>(
        src, Mr, bI, PzB, PhB, WzT, WhT, dst,
        (d == 1) ? hOutF : nullptr);

    src = dst;
    dst = (d == 0) ? HGa : HGb;
  }
  const bf16_t* hFinal = HGa;   // d=1: src was HGb, dst was HGa

  nm_gather<<<2500, 256, 0, stream>>>(hFinal, aI, NM);

  // out = relu(fnode@Wo1 + NM@Wo2 + bo), row0 = 0   -> f32
  mgemm<256, 128, 2><<<313, 512, 0, stream>>>(
      fnodeH, fnodeF, 256, 1, NM, WoT, nullptr, 384, flags,
      boB, nullptr, nullptr, nullptr, nullptr, 128, out0F, N_);
}